// Round 2
// baseline (770.004 us; speedup 1.0000x reference)
//
#include <hip/hip_runtime.h>
#include <hip/hip_bf16.h>

#define BATCH   8192
#define NM      128      // n_models
#define NF      32       // n_feat
#define L1      64
#define L2O     32
#define L3O     16
#define INSZ    512
#define SB      16       // batch chunks per model
#define RPC     (BATCH/SB)   // 512 rows per chunk
#define EPSV    1e-5f

// ---------------- K1: stats of z1 (gather + dense1) ----------------
__global__ __launch_bounds__(256) void k_stats1(
    const float* __restrict__ x, const int* __restrict__ uf,
    const float* __restrict__ W1, const float* __restrict__ b1,
    float* __restrict__ sum1p, float* __restrict__ sq1p)
{
    __shared__ __align__(16) float sW1[NF*L1];
    __shared__ __align__(16) float sFeat[8][NF];
    __shared__ int sIdx[NF];
    __shared__ float sRed[L1][4][2];
    const int m = blockIdx.x >> 4;          // / SB
    const int c = blockIdx.x & (SB-1);
    const int t = threadIdx.x;
    for (int i = t; i < NF*L1; i += 256) sW1[i] = W1[m*NF*L1 + i];
    if (t < NF) sIdx[t] = uf[m*NF + t];
    __syncthreads();
    const int o = t & 63, r = t >> 6;       // output col, row-group
    float wcol[NF];
    #pragma unroll
    for (int i = 0; i < NF; ++i) wcol[i] = sW1[i*L1 + o];
    const float bias = b1[m*L1 + o];
    float sum = 0.f, sq = 0.f;
    const int row0 = c * RPC;
    const int rr = t >> 5, j = t & 31;      // gather mapping
    for (int stage = 0; stage < RPC/8; ++stage) {
        __syncthreads();                    // prev readers of sFeat done
        sFeat[rr][j] = x[(row0 + stage*8 + rr)*INSZ + sIdx[j]];
        __syncthreads();
        #pragma unroll
        for (int k = 0; k < 2; ++k) {
            const float4* fv = (const float4*)(&sFeat[r + k*4][0]);
            float acc = bias;
            #pragma unroll
            for (int ii = 0; ii < NF/4; ++ii) {
                float4 f4 = fv[ii];
                acc += f4.x*wcol[ii*4+0] + f4.y*wcol[ii*4+1]
                     + f4.z*wcol[ii*4+2] + f4.w*wcol[ii*4+3];
            }
            sum += acc; sq += acc*acc;
        }
    }
    sRed[o][r][0] = sum; sRed[o][r][1] = sq;
    __syncthreads();
    if (t < L1) {
        float S = 0.f, Q = 0.f;
        #pragma unroll
        for (int g = 0; g < 4; ++g) { S += sRed[t][g][0]; Q += sRed[t][g][1]; }
        sum1p[(m*L1 + t)*SB + c] = S;
        sq1p [(m*L1 + t)*SB + c] = Q;
    }
}

// ---------------- K2: finalize BN stats -> scale/shift ----------------
__global__ __launch_bounds__(256) void k_finalize(
    const float* __restrict__ sump, const float* __restrict__ sqp,
    const float* __restrict__ gamma, const float* __restrict__ beta,
    float* __restrict__ scale, float* __restrict__ shift, int nfeat)
{
    int f = blockIdx.x*256 + threadIdx.x;
    if (f >= nfeat) return;
    float S = 0.f, Q = 0.f;
    #pragma unroll
    for (int c = 0; c < SB; ++c) { S += sump[f*SB + c]; Q += sqp[f*SB + c]; }
    float mean = S * (1.f/BATCH);
    float var  = Q * (1.f/BATCH) - mean*mean;
    float rstd = rsqrtf(var + EPSV);
    float sc = rstd * gamma[f];
    scale[f] = sc;
    shift[f] = beta[f] - mean*sc;
}

// ---------------- K3: recompute z1, BN1+ReLU, dense2 -> stats of z2 ----------------
__global__ __launch_bounds__(256) void k_stats2(
    const float* __restrict__ x, const int* __restrict__ uf,
    const float* __restrict__ W1, const float* __restrict__ b1,
    const float* __restrict__ scale1, const float* __restrict__ shift1,
    const float* __restrict__ W2, const float* __restrict__ b2,
    float* __restrict__ sum2p, float* __restrict__ sq2p)
{
    __shared__ __align__(16) float sW1[NF*L1];
    __shared__ __align__(16) float sFeat[8][NF];
    __shared__ __align__(16) float sH1[8][L1];
    __shared__ int sIdx[NF];
    __shared__ float sB1[L1], sSc[L1], sSh[L1];
    __shared__ float sRed[L2O][8][2];
    const int m = blockIdx.x >> 4, c = blockIdx.x & 15, t = threadIdx.x;
    for (int i = t; i < NF*L1; i += 256) sW1[i] = W1[m*NF*L1 + i];
    if (t < NF) sIdx[t] = uf[m*NF + t];
    if (t < L1) { sB1[t] = b1[m*L1+t]; sSc[t] = scale1[m*L1+t]; sSh[t] = shift1[m*L1+t]; }
    const int o2 = t & 31, r8 = t >> 5;
    float wcol2[L1];
    #pragma unroll
    for (int i = 0; i < L1; ++i) wcol2[i] = W2[m*L1*L2O + i*L2O + o2];
    const float b2v = b2[m*L2O + o2];
    __syncthreads();
    const int o1 = t & 63, r4 = t >> 6;
    float wcol1[NF];
    #pragma unroll
    for (int i = 0; i < NF; ++i) wcol1[i] = sW1[i*L1 + o1];
    const float b1v = sB1[o1], scv = sSc[o1], shv = sSh[o1];
    float sum = 0.f, sq = 0.f;
    const int row0 = c * RPC;
    const int rr = t >> 5, j = t & 31;
    for (int stage = 0; stage < RPC/8; ++stage) {
        __syncthreads();
        sFeat[rr][j] = x[(row0 + stage*8 + rr)*INSZ + sIdx[j]];
        __syncthreads();
        #pragma unroll
        for (int k = 0; k < 2; ++k) {
            const int rrow = r4 + k*4;
            const float4* fv = (const float4*)(&sFeat[rrow][0]);
            float acc = b1v;
            #pragma unroll
            for (int ii = 0; ii < NF/4; ++ii) {
                float4 f4 = fv[ii];
                acc += f4.x*wcol1[ii*4+0] + f4.y*wcol1[ii*4+1]
                     + f4.z*wcol1[ii*4+2] + f4.w*wcol1[ii*4+3];
            }
            float h = acc*scv + shv;
            sH1[rrow][o1] = h > 0.f ? h : 0.f;
        }
        __syncthreads();
        {
            const float4* hv = (const float4*)(&sH1[r8][0]);
            float acc = b2v;
            #pragma unroll
            for (int ii = 0; ii < L1/4; ++ii) {
                float4 h4 = hv[ii];
                acc += h4.x*wcol2[ii*4+0] + h4.y*wcol2[ii*4+1]
                     + h4.z*wcol2[ii*4+2] + h4.w*wcol2[ii*4+3];
            }
            sum += acc; sq += acc*acc;
        }
    }
    sRed[o2][r8][0] = sum; sRed[o2][r8][1] = sq;
    __syncthreads();
    if (t < L2O) {
        float S = 0.f, Q = 0.f;
        #pragma unroll
        for (int g = 0; g < 8; ++g) { S += sRed[t][g][0]; Q += sRed[t][g][1]; }
        sum2p[(m*L2O + t)*SB + c] = S;
        sq2p [(m*L2O + t)*SB + c] = Q;
    }
}

// ---------------- K4: full recompute -> pred + per-model out partials ----------------
__global__ __launch_bounds__(256) void k_final(
    const float* __restrict__ x, const int* __restrict__ uf,
    const float* __restrict__ W1, const float* __restrict__ b1,
    const float* __restrict__ scale1, const float* __restrict__ shift1,
    const float* __restrict__ W2, const float* __restrict__ b2,
    const float* __restrict__ scale2, const float* __restrict__ shift2,
    const float* __restrict__ W3, const float* __restrict__ b3,
    const float* __restrict__ ow,
    float* __restrict__ pred, float* __restrict__ outpart)
{
    __shared__ __align__(16) float sW1[NF*L1];
    __shared__ __align__(16) float sFeat[8][NF];
    __shared__ __align__(16) float sH1[8][L1];
    __shared__ __align__(16) float sH2[8][L2O];
    __shared__ float sOut[8][L3O];
    __shared__ int sIdx[NF];
    __shared__ float sB1[L1], sSc[L1], sSh[L1];
    const int m = blockIdx.x >> 4, c = blockIdx.x & 15, t = threadIdx.x;
    for (int i = t; i < NF*L1; i += 256) sW1[i] = W1[m*NF*L1 + i];
    if (t < NF) sIdx[t] = uf[m*NF + t];
    if (t < L1) { sB1[t] = b1[m*L1+t]; sSc[t] = scale1[m*L1+t]; sSh[t] = shift1[m*L1+t]; }
    const int o2 = t & 31, r8 = t >> 5;
    float wcol2[L1];
    #pragma unroll
    for (int i = 0; i < L1; ++i) wcol2[i] = W2[m*L1*L2O + i*L2O + o2];
    const float b2v = b2[m*L2O + o2];
    const float sc2 = scale2[m*L2O + o2], sh2 = shift2[m*L2O + o2];
    const int o3 = t & 15, r16 = t >> 4;
    float wcol3[NF];
    #pragma unroll
    for (int i = 0; i < L2O; ++i) wcol3[i] = W3[m*L2O*L3O + i*L3O + o3];
    const float b3v = b3[m*L3O + o3];
    const float owv = ow[m*L3O + o3];
    __syncthreads();
    const int o1 = t & 63, r4 = t >> 6;
    float wcol1[NF];
    #pragma unroll
    for (int i = 0; i < NF; ++i) wcol1[i] = sW1[i*L1 + o1];
    const float b1v = sB1[o1], scv = sSc[o1], shv = sSh[o1];
    const int row0 = c * RPC;
    const int rr = t >> 5, j = t & 31;
    for (int stage = 0; stage < RPC/8; ++stage) {
        __syncthreads();
        sFeat[rr][j] = x[(row0 + stage*8 + rr)*INSZ + sIdx[j]];
        __syncthreads();
        #pragma unroll
        for (int k = 0; k < 2; ++k) {
            const int rrow = r4 + k*4;
            const float4* fv = (const float4*)(&sFeat[rrow][0]);
            float acc = b1v;
            #pragma unroll
            for (int ii = 0; ii < NF/4; ++ii) {
                float4 f4 = fv[ii];
                acc += f4.x*wcol1[ii*4+0] + f4.y*wcol1[ii*4+1]
                     + f4.z*wcol1[ii*4+2] + f4.w*wcol1[ii*4+3];
            }
            float h = acc*scv + shv;
            sH1[rrow][o1] = h > 0.f ? h : 0.f;
        }
        __syncthreads();
        {
            const float4* hv = (const float4*)(&sH1[r8][0]);
            float acc = b2v;
            #pragma unroll
            for (int ii = 0; ii < L1/4; ++ii) {
                float4 h4 = hv[ii];
                acc += h4.x*wcol2[ii*4+0] + h4.y*wcol2[ii*4+1]
                     + h4.z*wcol2[ii*4+2] + h4.w*wcol2[ii*4+3];
            }
            float h = acc*sc2 + sh2;
            sH2[r8][o2] = h > 0.f ? h : 0.f;
        }
        __syncthreads();
        if (t < 128) {
            const float4* hv = (const float4*)(&sH2[r16][0]);
            float acc = b3v;
            #pragma unroll
            for (int ii = 0; ii < L2O/4; ++ii) {
                float4 h4 = hv[ii];
                acc += h4.x*wcol3[ii*4+0] + h4.y*wcol3[ii*4+1]
                     + h4.z*wcol3[ii*4+2] + h4.w*wcol3[ii*4+3];
            }
            const int row = row0 + stage*8 + r16;
            pred[row*(NM*L3O) + m*L3O + o3] = acc;
            sOut[r16][o3] = acc * owv;
        }
        __syncthreads();
        if (t < 8) {
            float s = 0.f;
            #pragma unroll
            for (int i = 0; i < L3O; ++i) s += sOut[t][i];
            outpart[(row0 + stage*8 + t)*NM + m] = s;
        }
    }
}

// ---------------- K5: out = sum over models + bias ----------------
__global__ __launch_bounds__(256) void k_out(
    const float* __restrict__ outpart, const float* __restrict__ ob,
    float* __restrict__ out)
{
    int b = blockIdx.x*256 + threadIdx.x;
    if (b >= BATCH) return;
    const float4* p = (const float4*)(outpart + (size_t)b*NM);
    float acc = 0.f;
    #pragma unroll
    for (int i = 0; i < NM/4; ++i) { float4 v = p[i]; acc += v.x + v.y + v.z + v.w; }
    out[b] = acc + ob[0];
}

extern "C" void kernel_launch(void* const* d_in, const int* in_sizes, int n_in,
                              void* d_out, int out_size, void* d_ws, size_t ws_size,
                              hipStream_t stream) {
    const float* x   = (const float*)d_in[0];
    const int*   uf  = (const int*  )d_in[1];
    const float* W1  = (const float*)d_in[2];
    const float* b1  = (const float*)d_in[3];
    const float* W2  = (const float*)d_in[4];
    const float* b2  = (const float*)d_in[5];
    const float* W3  = (const float*)d_in[6];
    const float* b3  = (const float*)d_in[7];
    const float* g1  = (const float*)d_in[8];
    const float* be1 = (const float*)d_in[9];
    const float* g2  = (const float*)d_in[10];
    const float* be2 = (const float*)d_in[11];
    const float* ow  = (const float*)d_in[12];
    const float* ob  = (const float*)d_in[13];

    float* out  = (float*)d_out;
    float* pred = out + BATCH;

    float* w = (float*)d_ws;
    float* sum1p  = w;                w += NM*L1*SB;     // 131072
    float* sq1p   = w;                w += NM*L1*SB;
    float* scale1 = w;                w += NM*L1;
    float* shift1 = w;                w += NM*L1;
    float* sum2p  = w;                w += NM*L2O*SB;
    float* sq2p   = w;                w += NM*L2O*SB;
    float* scale2 = w;                w += NM*L2O;
    float* shift2 = w;                w += NM*L2O;
    float* outpart= w;                w += BATCH*NM;

    k_stats1<<<NM*SB, 256, 0, stream>>>(x, uf, W1, b1, sum1p, sq1p);
    k_finalize<<<(NM*L1+255)/256, 256, 0, stream>>>(sum1p, sq1p, g1, be1, scale1, shift1, NM*L1);
    k_stats2<<<NM*SB, 256, 0, stream>>>(x, uf, W1, b1, scale1, shift1, W2, b2, sum2p, sq2p);
    k_finalize<<<(NM*L2O+255)/256, 256, 0, stream>>>(sum2p, sq2p, g2, be2, scale2, shift2, NM*L2O);
    k_final<<<NM*SB, 256, 0, stream>>>(x, uf, W1, b1, scale1, shift1, W2, b2,
                                       scale2, shift2, W3, b3, ow, pred, outpart);
    k_out<<<BATCH/256, 256, 0, stream>>>(outpart, ob, out);
}

// Round 3
// 116.348 us; speedup vs baseline: 6.6181x; 6.6181x over previous
//
#include <hip/hip_runtime.h>
#include <hip/hip_bf16.h>

#define BATCH   8192
#define NM      128      // n_models
#define NF      32       // n_feat
#define L1      64
#define L2O     32
#define L3O     16
#define INSZ    512
#define SB      16       // batch chunks (fallback path)
#define RPC     (BATCH/SB)
#define EPSV    1e-5f
#define CH      16       // chunks per model (mfma path)
#define PARTS   (CH*4)   // partials per feature (chunk x wave)

typedef __attribute__((ext_vector_type(8))) short short8;
typedef __attribute__((ext_vector_type(4))) float f32x4;

__device__ inline unsigned short f2bf(float f) {
    union { float f; unsigned u; } v; v.f = f;
    unsigned r = (v.u + 0x7FFF + ((v.u >> 16) & 1)) >> 16;
    return (unsigned short)r;
}

// =================== MFMA PATH ===================

// gather + bf16 convert: Ag[rb][m][r(16)][j(32)] bf16, rb = row/16
__global__ __launch_bounds__(256) void k_gather(
    const float* __restrict__ x, const int* __restrict__ uf,
    unsigned short* __restrict__ Ag)
{
    __shared__ float xs[16*INSZ];     // 32 KB
    __shared__ int   sUf[NM*NF];      // 16 KB
    const int rb = blockIdx.x;        // 0..511
    const int t  = threadIdx.x;
    const float4* xsrc = (const float4*)(x + (size_t)rb*16*INSZ);
    float4* xdst = (float4*)xs;
    #pragma unroll
    for (int p = 0; p < 8; ++p) xdst[t + p*256] = xsrc[t + p*256];
    const int4* us = (const int4*)uf;
    int4* ud = (int4*)sUf;
    #pragma unroll
    for (int p = 0; p < 4; ++p) ud[t + p*256] = us[t + p*256];
    __syncthreads();
    unsigned* outp = (unsigned*)(Ag + (size_t)rb*NM*512);
    const int e = t*2, r = e >> 5, j = e & 31;
    for (int m = 0; m < NM; ++m) {
        const int i0 = sUf[m*NF + j], i1 = sUf[m*NF + j + 1];
        const float g0 = xs[r*INSZ + i0], g1 = xs[r*INSZ + i1];
        outp[m*256 + t] = (unsigned)f2bf(g0) | ((unsigned)f2bf(g1) << 16);
    }
}

// stats of raw z1 (no bias; bias folded in finalize)
__global__ __launch_bounds__(256) void k_stats1_m(
    const unsigned short* __restrict__ Ag, const float* __restrict__ W1,
    float* __restrict__ sum1p, float* __restrict__ sq1p)
{
    const int m = blockIdx.x >> 4, chunk = blockIdx.x & 15;
    const int t = threadIdx.x, w = t >> 6, l = t & 63;
    const int lr = l & 15, lg = l >> 4;
    short8 w1f[4];
    #pragma unroll
    for (int n = 0; n < 4; ++n)
        #pragma unroll
        for (int s = 0; s < 8; ++s)
            w1f[n][s] = (short)f2bf(W1[(size_t)m*NF*L1 + (lg*8+s)*L1 + n*16 + lr]);
    float sum[4] = {0,0,0,0}, sq[4] = {0,0,0,0};
    for (int i = 0; i < 8; ++i) {
        const int rbG = chunk*32 + i*4 + w;
        const short8 a = *(const short8*)(Ag + ((size_t)rbG*NM + m)*512 + lr*32 + lg*8);
        #pragma unroll
        for (int n = 0; n < 4; ++n) {
            f32x4 acc = {0.f,0.f,0.f,0.f};
            acc = __builtin_amdgcn_mfma_f32_16x16x32_bf16(a, w1f[n], acc, 0, 0, 0);
            sum[n] += (acc[0]+acc[1]) + (acc[2]+acc[3]);
            sq[n]  += acc[0]*acc[0] + acc[1]*acc[1] + acc[2]*acc[2] + acc[3]*acc[3];
        }
    }
    #pragma unroll
    for (int n = 0; n < 4; ++n) {
        sum[n] += __shfl_xor(sum[n], 16); sum[n] += __shfl_xor(sum[n], 32);
        sq[n]  += __shfl_xor(sq[n], 16);  sq[n]  += __shfl_xor(sq[n], 32);
    }
    if (l < 16) {
        const int slot = chunk*4 + w;
        #pragma unroll
        for (int n = 0; n < 4; ++n) {
            const int f = m*L1 + n*16 + l;
            sum1p[(size_t)f*PARTS + slot] = sum[n];
            sq1p [(size_t)f*PARTS + slot] = sq[n];
        }
    }
}

__global__ __launch_bounds__(256) void k_finalize_m(
    const float* __restrict__ sump, const float* __restrict__ sqp,
    const float* __restrict__ bias, const float* __restrict__ gamma,
    const float* __restrict__ beta, float* __restrict__ scale,
    float* __restrict__ shift, int nfeat)
{
    int f = blockIdx.x*256 + threadIdx.x;
    if (f >= nfeat) return;
    float S = 0.f, Q = 0.f;
    #pragma unroll 8
    for (int c = 0; c < PARTS; ++c) { S += sump[(size_t)f*PARTS+c]; Q += sqp[(size_t)f*PARTS+c]; }
    float mz   = S * (1.f/BATCH);
    float var  = Q * (1.f/BATCH) - mz*mz;     // shift-invariant
    float mean = mz + bias[f];
    float sc   = rsqrtf(var + EPSV) * gamma[f];
    scale[f] = sc; shift[f] = beta[f] - mean*sc;
}

// recompute z1 -> BN1+ReLU -> dense2, stats of raw z2
__global__ __launch_bounds__(256) void k_stats2_m(
    const unsigned short* __restrict__ Ag, const float* __restrict__ W1,
    const float* __restrict__ scale1, const float* __restrict__ shift1,
    const float* __restrict__ W2,
    float* __restrict__ sum2p, float* __restrict__ sq2p)
{
    __shared__ unsigned short h1T[4][16*72];   // per-wave, pad 72 (2-way banks)
    const int m = blockIdx.x >> 4, chunk = blockIdx.x & 15;
    const int t = threadIdx.x, w = t >> 6, l = t & 63;
    const int lr = l & 15, lg = l >> 4;
    short8 w1f[4];
    #pragma unroll
    for (int n = 0; n < 4; ++n)
        #pragma unroll
        for (int s = 0; s < 8; ++s)
            w1f[n][s] = (short)f2bf(W1[(size_t)m*NF*L1 + (lg*8+s)*L1 + n*16 + lr]);
    float sc1[4], sh1[4];
    #pragma unroll
    for (int n = 0; n < 4; ++n) {
        sc1[n] = scale1[m*L1 + n*16 + lr];
        sh1[n] = shift1[m*L1 + n*16 + lr];
    }
    short8 w2f[2][2];
    #pragma unroll
    for (int n2 = 0; n2 < 2; ++n2)
        #pragma unroll
        for (int ks = 0; ks < 2; ++ks)
            #pragma unroll
            for (int s = 0; s < 8; ++s)
                w2f[n2][ks][s] = (short)f2bf(W2[(size_t)m*L1*L2O + (ks*32+lg*8+s)*L2O + n2*16 + lr]);
    unsigned short* hT = &h1T[w][0];
    float sum[2] = {0,0}, sq[2] = {0,0};
    for (int i = 0; i < 8; ++i) {
        const int rbG = chunk*32 + i*4 + w;
        const short8 a = *(const short8*)(Ag + ((size_t)rbG*NM + m)*512 + lr*32 + lg*8);
        #pragma unroll
        for (int n = 0; n < 4; ++n) {
            f32x4 acc = {0.f,0.f,0.f,0.f};
            acc = __builtin_amdgcn_mfma_f32_16x16x32_bf16(a, w1f[n], acc, 0, 0, 0);
            #pragma unroll
            for (int r = 0; r < 4; ++r) {
                float h = acc[r]*sc1[n] + sh1[n];
                hT[(lg*4+r)*72 + n*16 + lr] = f2bf(h > 0.f ? h : 0.f);
            }
        }
        #pragma unroll
        for (int n2 = 0; n2 < 2; ++n2) {
            f32x4 acc = {0.f,0.f,0.f,0.f};
            #pragma unroll
            for (int ks = 0; ks < 2; ++ks) {
                const short8 a2 = *(const short8*)(hT + lr*72 + ks*32 + lg*8);
                acc = __builtin_amdgcn_mfma_f32_16x16x32_bf16(a2, w2f[n2][ks], acc, 0, 0, 0);
            }
            sum[n2] += (acc[0]+acc[1]) + (acc[2]+acc[3]);
            sq[n2]  += acc[0]*acc[0] + acc[1]*acc[1] + acc[2]*acc[2] + acc[3]*acc[3];
        }
    }
    #pragma unroll
    for (int n2 = 0; n2 < 2; ++n2) {
        sum[n2] += __shfl_xor(sum[n2], 16); sum[n2] += __shfl_xor(sum[n2], 32);
        sq[n2]  += __shfl_xor(sq[n2], 16);  sq[n2]  += __shfl_xor(sq[n2], 32);
    }
    if (l < 16) {
        const int slot = chunk*4 + w;
        #pragma unroll
        for (int n2 = 0; n2 < 2; ++n2) {
            const int f = m*L2O + n2*16 + l;
            sum2p[(size_t)f*PARTS + slot] = sum[n2];
            sq2p [(size_t)f*PARTS + slot] = sq[n2];
        }
    }
}

// full recompute -> pred + per-model out partials
__global__ __launch_bounds__(256) void k_final_m(
    const unsigned short* __restrict__ Ag, const float* __restrict__ W1,
    const float* __restrict__ scale1, const float* __restrict__ shift1,
    const float* __restrict__ W2,
    const float* __restrict__ scale2, const float* __restrict__ shift2,
    const float* __restrict__ W3, const float* __restrict__ b3,
    const float* __restrict__ ow,
    float* __restrict__ pred, float* __restrict__ outpart)
{
    __shared__ unsigned short h1T[4][16*72];
    __shared__ unsigned short h2T[4][16*40];
    const int m = blockIdx.x >> 4, chunk = blockIdx.x & 15;
    const int t = threadIdx.x, w = t >> 6, l = t & 63;
    const int lr = l & 15, lg = l >> 4;
    short8 w1f[4];
    #pragma unroll
    for (int n = 0; n < 4; ++n)
        #pragma unroll
        for (int s = 0; s < 8; ++s)
            w1f[n][s] = (short)f2bf(W1[(size_t)m*NF*L1 + (lg*8+s)*L1 + n*16 + lr]);
    float sc1[4], sh1[4];
    #pragma unroll
    for (int n = 0; n < 4; ++n) {
        sc1[n] = scale1[m*L1 + n*16 + lr];
        sh1[n] = shift1[m*L1 + n*16 + lr];
    }
    short8 w2f[2][2];
    #pragma unroll
    for (int n2 = 0; n2 < 2; ++n2)
        #pragma unroll
        for (int ks = 0; ks < 2; ++ks)
            #pragma unroll
            for (int s = 0; s < 8; ++s)
                w2f[n2][ks][s] = (short)f2bf(W2[(size_t)m*L1*L2O + (ks*32+lg*8+s)*L2O + n2*16 + lr]);
    float sc2[2], sh2[2];
    #pragma unroll
    for (int n2 = 0; n2 < 2; ++n2) {
        sc2[n2] = scale2[m*L2O + n2*16 + lr];
        sh2[n2] = shift2[m*L2O + n2*16 + lr];
    }
    short8 w3f;
    #pragma unroll
    for (int s = 0; s < 8; ++s)
        w3f[s] = (short)f2bf(W3[(size_t)m*L2O*L3O + (lg*8+s)*L3O + lr]);
    const float b3v = b3[m*L3O + lr];
    const float owv = ow[m*L3O + lr];
    unsigned short* hT  = &h1T[w][0];
    unsigned short* hT2 = &h2T[w][0];
    for (int i = 0; i < 8; ++i) {
        const int rbG = chunk*32 + i*4 + w;
        const short8 a = *(const short8*)(Ag + ((size_t)rbG*NM + m)*512 + lr*32 + lg*8);
        #pragma unroll
        for (int n = 0; n < 4; ++n) {
            f32x4 acc = {0.f,0.f,0.f,0.f};
            acc = __builtin_amdgcn_mfma_f32_16x16x32_bf16(a, w1f[n], acc, 0, 0, 0);
            #pragma unroll
            for (int r = 0; r < 4; ++r) {
                float h = acc[r]*sc1[n] + sh1[n];
                hT[(lg*4+r)*72 + n*16 + lr] = f2bf(h > 0.f ? h : 0.f);
            }
        }
        #pragma unroll
        for (int n2 = 0; n2 < 2; ++n2) {
            f32x4 acc = {0.f,0.f,0.f,0.f};
            #pragma unroll
            for (int ks = 0; ks < 2; ++ks) {
                const short8 a2 = *(const short8*)(hT + lr*72 + ks*32 + lg*8);
                acc = __builtin_amdgcn_mfma_f32_16x16x32_bf16(a2, w2f[n2][ks], acc, 0, 0, 0);
            }
            #pragma unroll
            for (int r = 0; r < 4; ++r) {
                float h = acc[r]*sc2[n2] + sh2[n2];
                hT2[(lg*4+r)*40 + n2*16 + lr] = f2bf(h > 0.f ? h : 0.f);
            }
        }
        {
            const short8 a3 = *(const short8*)(hT2 + lr*40 + lg*8);
            f32x4 acc = {0.f,0.f,0.f,0.f};
            acc = __builtin_amdgcn_mfma_f32_16x16x32_bf16(a3, w3f, acc, 0, 0, 0);
            #pragma unroll
            for (int r = 0; r < 4; ++r) {
                const float pv = acc[r] + b3v;
                const size_t row = (size_t)rbG*16 + lg*4 + r;
                pred[row*(NM*L3O) + m*L3O + lr] = pv;
                float v = pv * owv;
                v += __shfl_xor(v, 1); v += __shfl_xor(v, 2);
                v += __shfl_xor(v, 4); v += __shfl_xor(v, 8);
                if (lr == 0) outpart[row*NM + m] = v;
            }
        }
    }
}

// =================== FALLBACK PATH (round-0, verified) ===================

__global__ __launch_bounds__(256) void k_stats1(
    const float* __restrict__ x, const int* __restrict__ uf,
    const float* __restrict__ W1, const float* __restrict__ b1,
    float* __restrict__ sum1p, float* __restrict__ sq1p)
{
    __shared__ __align__(16) float sW1[NF*L1];
    __shared__ __align__(16) float sFeat[8][NF];
    __shared__ int sIdx[NF];
    __shared__ float sRed[L1][4][2];
    const int m = blockIdx.x >> 4;
    const int c = blockIdx.x & (SB-1);
    const int t = threadIdx.x;
    for (int i = t; i < NF*L1; i += 256) sW1[i] = W1[m*NF*L1 + i];
    if (t < NF) sIdx[t] = uf[m*NF + t];
    __syncthreads();
    const int o = t & 63, r = t >> 6;
    float wcol[NF];
    #pragma unroll
    for (int i = 0; i < NF; ++i) wcol[i] = sW1[i*L1 + o];
    const float bias = b1[m*L1 + o];
    float sum = 0.f, sq = 0.f;
    const int row0 = c * RPC;
    const int rr = t >> 5, j = t & 31;
    for (int stage = 0; stage < RPC/8; ++stage) {
        __syncthreads();
        sFeat[rr][j] = x[(row0 + stage*8 + rr)*INSZ + sIdx[j]];
        __syncthreads();
        #pragma unroll
        for (int k = 0; k < 2; ++k) {
            const float4* fv = (const float4*)(&sFeat[r + k*4][0]);
            float acc = bias;
            #pragma unroll
            for (int ii = 0; ii < NF/4; ++ii) {
                float4 f4 = fv[ii];
                acc += f4.x*wcol[ii*4+0] + f4.y*wcol[ii*4+1]
                     + f4.z*wcol[ii*4+2] + f4.w*wcol[ii*4+3];
            }
            sum += acc; sq += acc*acc;
        }
    }
    sRed[o][r][0] = sum; sRed[o][r][1] = sq;
    __syncthreads();
    if (t < L1) {
        float S = 0.f, Q = 0.f;
        #pragma unroll
        for (int g = 0; g < 4; ++g) { S += sRed[t][g][0]; Q += sRed[t][g][1]; }
        sum1p[(m*L1 + t)*SB + c] = S;
        sq1p [(m*L1 + t)*SB + c] = Q;
    }
}

__global__ __launch_bounds__(256) void k_finalize(
    const float* __restrict__ sump, const float* __restrict__ sqp,
    const float* __restrict__ gamma, const float* __restrict__ beta,
    float* __restrict__ scale, float* __restrict__ shift, int nfeat)
{
    int f = blockIdx.x*256 + threadIdx.x;
    if (f >= nfeat) return;
    float S = 0.f, Q = 0.f;
    #pragma unroll
    for (int c = 0; c < SB; ++c) { S += sump[f*SB + c]; Q += sqp[f*SB + c]; }
    float mean = S * (1.f/BATCH);
    float var  = Q * (1.f/BATCH) - mean*mean;
    float rstd = rsqrtf(var + EPSV);
    float sc = rstd * gamma[f];
    scale[f] = sc;
    shift[f] = beta[f] - mean*sc;
}

__global__ __launch_bounds__(256) void k_stats2(
    const float* __restrict__ x, const int* __restrict__ uf,
    const float* __restrict__ W1, const float* __restrict__ b1,
    const float* __restrict__ scale1, const float* __restrict__ shift1,
    const float* __restrict__ W2, const float* __restrict__ b2,
    float* __restrict__ sum2p, float* __restrict__ sq2p)
{
    __shared__ __align__(16) float sW1[NF*L1];
    __shared__ __align__(16) float sFeat[8][NF];
    __shared__ __align__(16) float sH1[8][L1];
    __shared__ int sIdx[NF];
    __shared__ float sB1[L1], sSc[L1], sSh[L1];
    __shared__ float sRed[L2O][8][2];
    const int m = blockIdx.x >> 4, c = blockIdx.x & 15, t = threadIdx.x;
    for (int i = t; i < NF*L1; i += 256) sW1[i] = W1[m*NF*L1 + i];
    if (t < NF) sIdx[t] = uf[m*NF + t];
    if (t < L1) { sB1[t] = b1[m*L1+t]; sSc[t] = scale1[m*L1+t]; sSh[t] = shift1[m*L1+t]; }
    const int o2 = t & 31, r8 = t >> 5;
    float wcol2[L1];
    #pragma unroll
    for (int i = 0; i < L1; ++i) wcol2[i] = W2[m*L1*L2O + i*L2O + o2];
    const float b2v = b2[m*L2O + o2];
    __syncthreads();
    const int o1 = t & 63, r4 = t >> 6;
    float wcol1[NF];
    #pragma unroll
    for (int i = 0; i < NF; ++i) wcol1[i] = sW1[i*L1 + o1];
    const float b1v = sB1[o1], scv = sSc[o1], shv = sSh[o1];
    float sum = 0.f, sq = 0.f;
    const int row0 = c * RPC;
    const int rr = t >> 5, j = t & 31;
    for (int stage = 0; stage < RPC/8; ++stage) {
        __syncthreads();
        sFeat[rr][j] = x[(row0 + stage*8 + rr)*INSZ + sIdx[j]];
        __syncthreads();
        #pragma unroll
        for (int k = 0; k < 2; ++k) {
            const int rrow = r4 + k*4;
            const float4* fv = (const float4*)(&sFeat[rrow][0]);
            float acc = b1v;
            #pragma unroll
            for (int ii = 0; ii < NF/4; ++ii) {
                float4 f4 = fv[ii];
                acc += f4.x*wcol1[ii*4+0] + f4.y*wcol1[ii*4+1]
                     + f4.z*wcol1[ii*4+2] + f4.w*wcol1[ii*4+3];
            }
            float h = acc*scv + shv;
            sH1[rrow][o1] = h > 0.f ? h : 0.f;
        }
        __syncthreads();
        {
            const float4* hv = (const float4*)(&sH1[r8][0]);
            float acc = b2v;
            #pragma unroll
            for (int ii = 0; ii < L1/4; ++ii) {
                float4 h4 = hv[ii];
                acc += h4.x*wcol2[ii*4+0] + h4.y*wcol2[ii*4+1]
                     + h4.z*wcol2[ii*4+2] + h4.w*wcol2[ii*4+3];
            }
            sum += acc; sq += acc*acc;
        }
    }
    sRed[o2][r8][0] = sum; sRed[o2][r8][1] = sq;
    __syncthreads();
    if (t < L2O) {
        float S = 0.f, Q = 0.f;
        #pragma unroll
        for (int g = 0; g < 8; ++g) { S += sRed[t][g][0]; Q += sRed[t][g][1]; }
        sum2p[(m*L2O + t)*SB + c] = S;
        sq2p [(m*L2O + t)*SB + c] = Q;
    }
}

__global__ __launch_bounds__(256) void k_final(
    const float* __restrict__ x, const int* __restrict__ uf,
    const float* __restrict__ W1, const float* __restrict__ b1,
    const float* __restrict__ scale1, const float* __restrict__ shift1,
    const float* __restrict__ W2, const float* __restrict__ b2,
    const float* __restrict__ scale2, const float* __restrict__ shift2,
    const float* __restrict__ W3, const float* __restrict__ b3,
    const float* __restrict__ ow,
    float* __restrict__ pred, float* __restrict__ outpart)
{
    __shared__ __align__(16) float sW1[NF*L1];
    __shared__ __align__(16) float sFeat[8][NF];
    __shared__ __align__(16) float sH1[8][L1];
    __shared__ __align__(16) float sH2[8][L2O];
    __shared__ float sOut[8][L3O];
    __shared__ int sIdx[NF];
    __shared__ float sB1[L1], sSc[L1], sSh[L1];
    const int m = blockIdx.x >> 4, c = blockIdx.x & 15, t = threadIdx.x;
    for (int i = t; i < NF*L1; i += 256) sW1[i] = W1[m*NF*L1 + i];
    if (t < NF) sIdx[t] = uf[m*NF + t];
    if (t < L1) { sB1[t] = b1[m*L1+t]; sSc[t] = scale1[m*L1+t]; sSh[t] = shift1[m*L1+t]; }
    const int o2 = t & 31, r8 = t >> 5;
    float wcol2[L1];
    #pragma unroll
    for (int i = 0; i < L1; ++i) wcol2[i] = W2[m*L1*L2O + i*L2O + o2];
    const float b2v = b2[m*L2O + o2];
    const float sc2 = scale2[m*L2O + o2], sh2 = shift2[m*L2O + o2];
    const int o3 = t & 15, r16 = t >> 4;
    float wcol3[NF];
    #pragma unroll
    for (int i = 0; i < L2O; ++i) wcol3[i] = W3[m*L2O*L3O + i*L3O + o3];
    const float b3v = b3[m*L3O + o3];
    const float owv = ow[m*L3O + o3];
    __syncthreads();
    const int o1 = t & 63, r4 = t >> 6;
    float wcol1[NF];
    #pragma unroll
    for (int i = 0; i < NF; ++i) wcol1[i] = sW1[i*L1 + o1];
    const float b1v = sB1[o1], scv = sSc[o1], shv = sSh[o1];
    const int row0 = c * RPC;
    const int rr = t >> 5, j = t & 31;
    for (int stage = 0; stage < RPC/8; ++stage) {
        __syncthreads();
        sFeat[rr][j] = x[(row0 + stage*8 + rr)*INSZ + sIdx[j]];
        __syncthreads();
        #pragma unroll
        for (int k = 0; k < 2; ++k) {
            const int rrow = r4 + k*4;
            const float4* fv = (const float4*)(&sFeat[rrow][0]);
            float acc = b1v;
            #pragma unroll
            for (int ii = 0; ii < NF/4; ++ii) {
                float4 f4 = fv[ii];
                acc += f4.x*wcol1[ii*4+0] + f4.y*wcol1[ii*4+1]
                     + f4.z*wcol1[ii*4+2] + f4.w*wcol1[ii*4+3];
            }
            float h = acc*scv + shv;
            sH1[rrow][o1] = h > 0.f ? h : 0.f;
        }
        __syncthreads();
        {
            const float4* hv = (const float4*)(&sH1[r8][0]);
            float acc = b2v;
            #pragma unroll
            for (int ii = 0; ii < L1/4; ++ii) {
                float4 h4 = hv[ii];
                acc += h4.x*wcol2[ii*4+0] + h4.y*wcol2[ii*4+1]
                     + h4.z*wcol2[ii*4+2] + h4.w*wcol2[ii*4+3];
            }
            float h = acc*sc2 + sh2;
            sH2[r8][o2] = h > 0.f ? h : 0.f;
        }
        __syncthreads();
        if (t < 128) {
            const float4* hv = (const float4*)(&sH2[r16][0]);
            float acc = b3v;
            #pragma unroll
            for (int ii = 0; ii < L2O/4; ++ii) {
                float4 h4 = hv[ii];
                acc += h4.x*wcol3[ii*4+0] + h4.y*wcol3[ii*4+1]
                     + h4.z*wcol3[ii*4+2] + h4.w*wcol3[ii*4+3];
            }
            const int row = row0 + stage*8 + r16;
            pred[row*(NM*L3O) + m*L3O + o3] = acc;
            sOut[r16][o3] = acc * owv;
        }
        __syncthreads();
        if (t < 8) {
            float s = 0.f;
            #pragma unroll
            for (int i = 0; i < L3O; ++i) s += sOut[t][i];
            outpart[(row0 + stage*8 + t)*NM + m] = s;
        }
    }
}

__global__ __launch_bounds__(256) void k_out(
    const float* __restrict__ outpart, const float* __restrict__ ob,
    float* __restrict__ out)
{
    int b = blockIdx.x*256 + threadIdx.x;
    if (b >= BATCH) return;
    const float4* p = (const float4*)(outpart + (size_t)b*NM);
    float acc = 0.f;
    #pragma unroll
    for (int i = 0; i < NM/4; ++i) { float4 v = p[i]; acc += v.x + v.y + v.z + v.w; }
    out[b] = acc + ob[0];
}

extern "C" void kernel_launch(void* const* d_in, const int* in_sizes, int n_in,
                              void* d_out, int out_size, void* d_ws, size_t ws_size,
                              hipStream_t stream) {
    const float* x   = (const float*)d_in[0];
    const int*   uf  = (const int*  )d_in[1];
    const float* W1  = (const float*)d_in[2];
    const float* b1  = (const float*)d_in[3];
    const float* W2  = (const float*)d_in[4];
    const float* b2  = (const float*)d_in[5];
    const float* W3  = (const float*)d_in[6];
    const float* b3  = (const float*)d_in[7];
    const float* g1  = (const float*)d_in[8];
    const float* be1 = (const float*)d_in[9];
    const float* g2  = (const float*)d_in[10];
    const float* be2 = (const float*)d_in[11];
    const float* ow  = (const float*)d_in[12];
    const float* ob  = (const float*)d_in[13];

    float* out  = (float*)d_out;
    float* pred = out + BATCH;

    // mfma path workspace demand
    const size_t agElems = (size_t)BATCH * NM * NF;            // bf16
    size_t need = agElems * 2;
    need += (size_t)(NM*L1*PARTS) * 4 * 2;     // sum1p/sq1p
    need += (size_t)(NM*L2O*PARTS) * 4 * 2;    // sum2p/sq2p
    need += (size_t)(NM*L1) * 4 * 2 + (size_t)(NM*L2O) * 4 * 2;
    need += (size_t)BATCH * NM * 4;            // outpart

    if (ws_size >= need) {
        unsigned short* Ag = (unsigned short*)d_ws;
        float* w = (float*)(Ag + agElems);
        float* sum1p  = w;  w += NM*L1*PARTS;
        float* sq1p   = w;  w += NM*L1*PARTS;
        float* sum2p  = w;  w += NM*L2O*PARTS;
        float* sq2p   = w;  w += NM*L2O*PARTS;
        float* scale1 = w;  w += NM*L1;
        float* shift1 = w;  w += NM*L1;
        float* scale2 = w;  w += NM*L2O;
        float* shift2 = w;  w += NM*L2O;
        float* outpart= w;  w += (size_t)BATCH*NM;

        k_gather<<<BATCH/16, 256, 0, stream>>>(x, uf, Ag);
        k_stats1_m<<<NM*CH, 256, 0, stream>>>(Ag, W1, sum1p, sq1p);
        k_finalize_m<<<(NM*L1+255)/256, 256, 0, stream>>>(sum1p, sq1p, b1, g1, be1, scale1, shift1, NM*L1);
        k_stats2_m<<<NM*CH, 256, 0, stream>>>(Ag, W1, scale1, shift1, W2, sum2p, sq2p);
        k_finalize_m<<<(NM*L2O+255)/256, 256, 0, stream>>>(sum2p, sq2p, b2, g2, be2, scale2, shift2, NM*L2O);
        k_final_m<<<NM*CH, 256, 0, stream>>>(Ag, W1, scale1, shift1, W2, scale2, shift2,
                                             W3, b3, ow, pred, outpart);
        k_out<<<BATCH/256, 256, 0, stream>>>(outpart, ob, out);
    } else {
        float* w = (float*)d_ws;
        float* sum1p  = w;  w += NM*L1*SB;
        float* sq1p   = w;  w += NM*L1*SB;
        float* scale1 = w;  w += NM*L1;
        float* shift1 = w;  w += NM*L1;
        float* sum2p  = w;  w += NM*L2O*SB;
        float* sq2p   = w;  w += NM*L2O*SB;
        float* scale2 = w;  w += NM*L2O;
        float* shift2 = w;  w += NM*L2O;
        float* outpart= w;  w += (size_t)BATCH*NM;

        k_stats1<<<NM*SB, 256, 0, stream>>>(x, uf, W1, b1, sum1p, sq1p);
        k_finalize<<<(NM*L1+255)/256, 256, 0, stream>>>(sum1p, sq1p, g1, be1, scale1, shift1, NM*L1);
        k_stats2<<<NM*SB, 256, 0, stream>>>(x, uf, W1, b1, scale1, shift1, W2, b2, sum2p, sq2p);
        k_finalize<<<(NM*L2O+255)/256, 256, 0, stream>>>(sum2p, sq2p, g2, be2, scale2, shift2, NM*L2O);
        k_final<<<NM*SB, 256, 0, stream>>>(x, uf, W1, b1, scale1, shift1, W2, b2,
                                           scale2, shift2, W3, b3, ow, pred, outpart);
        k_out<<<BATCH/256, 256, 0, stream>>>(outpart, ob, out);
    }
}

// Round 4
// 107.518 us; speedup vs baseline: 7.1616x; 1.0821x over previous
//
#include <hip/hip_runtime.h>
#include <hip/hip_bf16.h>

#define BATCH   8192
#define NM      128      // n_models
#define NF      32       // n_feat
#define L1      64
#define L2O     32
#define L3O     16
#define INSZ    512
#define EPSV    1e-5f
#define CH      16       // chunks per model (stats2/final blocks)
#define P64     64       // partial slots, f-major layout (paths B + stats2)
#define GS1B    256      // k_gs1 blocks (path A), 32 rows each
#define XS_STR  522      // padded LDS stride (ushorts): 261 dwords, odd->bank spread

typedef __attribute__((ext_vector_type(8))) short short8;
typedef __attribute__((ext_vector_type(4))) float f32x4;

union U8 { short8 s8; unsigned u[4]; };

__device__ inline unsigned short f2bf(float f) {
    union { float f; unsigned u; } v; v.f = f;
    return (unsigned short)((v.u + 0x7FFF + ((v.u >> 16) & 1)) >> 16);
}
__device__ inline unsigned pkbf(float a, float b) {
    union { __hip_bfloat162 h; unsigned u; } c;
    c.h = __float22bfloat162_rn(float2{a, b});
    return c.u;
}

// ---------- k_prep: pack W1/W2/W3 to bf16 fragment order ----------
// W1p[m][n*512 + l*8 + s] = W1[m][k=(l>>4)*8+s][o=n*16+(l&15)]
// W2p[m][(n2*2+ks)*512 + l*8 + s] = W2[m][k=ks*32+(l>>4)*8+s][o=n2*16+(l&15)]
// W3p[m][l*8 + s] = W3[m][k=(l>>4)*8+s][o=l&15]
__global__ __launch_bounds__(256) void k_prep(
    const float* __restrict__ W1, const float* __restrict__ W2,
    const float* __restrict__ W3,
    unsigned short* __restrict__ W1p, unsigned short* __restrict__ W2p,
    unsigned short* __restrict__ W3p)
{
    int g = blockIdx.x*256 + threadIdx.x;      // NM*4608 total
    int m = g / 4608, r = g % 4608;
    if (r < 2048) {
        int n = r >> 9, l = (r >> 3) & 63, s = r & 7;
        W1p[m*2048 + r] = f2bf(W1[m*2048 + ((l>>4)*8+s)*L1 + n*16 + (l&15)]);
    } else if (r < 4096) {
        int q = r - 2048;
        int f = q >> 9, l = (q >> 3) & 63, s = q & 7;
        int n2 = f >> 1, ks = f & 1;
        W2p[m*2048 + q] = f2bf(W2[m*2048 + (ks*32+(l>>4)*8+s)*L2O + n2*16 + (l&15)]);
    } else {
        int q = r - 4096;
        int l = (q >> 3) & 63, s = q & 7;
        W3p[m*512 + q] = f2bf(W3[m*512 + ((l>>4)*8+s)*L3O + (l&15)]);
    }
}

// ---------- k_gs1 (path A): fused gather + Ag write + stats1 partials ----------
// 512 threads, 8 waves; block = 32 rows; wave owns models w*16..w*16+15.
// partials slot-major: s1sum[blk*8192 + f]
__global__ __launch_bounds__(512) void k_gs1(
    const float* __restrict__ x, const int* __restrict__ uf,
    const unsigned short* __restrict__ W1p,
    unsigned short* __restrict__ Ag,
    float* __restrict__ s1sum, float* __restrict__ s1sq)
{
    __shared__ unsigned short xs[32*XS_STR];   // 33.4 KB
    __shared__ int sUf[NM*NF];                 // 16 KB
    const int blk = blockIdx.x, t = threadIdx.x;
    // stage 32 x-rows as bf16 (padded stride)
    #pragma unroll
    for (int p = 0; p < 8; ++p) {
        const float4 v = *(const float4*)(x + (size_t)blk*32*INSZ + p*2048 + t*4);
        const int row = 4*p + (t>>7), col = (t&127)*4;
        *(unsigned*)(&xs[row*XS_STR + col])     = pkbf(v.x, v.y);
        *(unsigned*)(&xs[row*XS_STR + col + 2]) = pkbf(v.z, v.w);
    }
    #pragma unroll
    for (int p = 0; p < 2; ++p)
        ((int4*)sUf)[t + p*512] = ((const int4*)uf)[t + p*512];
    __syncthreads();

    const int w = t >> 6, l = t & 63, lr = l & 15, lg = l >> 4;
    const unsigned short* xr0 = xs + lr*XS_STR;
    const unsigned short* xr1 = xs + (16+lr)*XS_STR;
    for (int mi = 0; mi < 16; ++mi) {
        const int m = w*16 + mi;
        const int4 ia = ((const int4*)sUf)[m*8 + lg*2];
        const int4 ib = ((const int4*)sUf)[m*8 + lg*2 + 1];
        U8 A0, A1;
        A0.u[0] = xr0[ia.x] | ((unsigned)xr0[ia.y] << 16);
        A0.u[1] = xr0[ia.z] | ((unsigned)xr0[ia.w] << 16);
        A0.u[2] = xr0[ib.x] | ((unsigned)xr0[ib.y] << 16);
        A0.u[3] = xr0[ib.z] | ((unsigned)xr0[ib.w] << 16);
        A1.u[0] = xr1[ia.x] | ((unsigned)xr1[ia.y] << 16);
        A1.u[1] = xr1[ia.z] | ((unsigned)xr1[ia.w] << 16);
        A1.u[2] = xr1[ib.x] | ((unsigned)xr1[ib.y] << 16);
        A1.u[3] = xr1[ib.z] | ((unsigned)xr1[ib.w] << 16);
        // Ag write-out (two 16-row blocks)
        *(short8*)(Ag + ((size_t)(blk*2  )*NM + m)*512 + lr*32 + lg*8) = A0.s8;
        *(short8*)(Ag + ((size_t)(blk*2+1)*NM + m)*512 + lr*32 + lg*8) = A1.s8;
        // stats
        float sum[4], sq[4];
        #pragma unroll
        for (int n = 0; n < 4; ++n) {
            const short8 wf = *(const short8*)(W1p + m*2048 + n*512 + l*8);
            f32x4 z = {0.f,0.f,0.f,0.f};
            f32x4 c0 = __builtin_amdgcn_mfma_f32_16x16x32_bf16(A0.s8, wf, z, 0, 0, 0);
            f32x4 c1 = __builtin_amdgcn_mfma_f32_16x16x32_bf16(A1.s8, wf, z, 0, 0, 0);
            sum[n] = (c0[0]+c0[1]) + (c0[2]+c0[3]) + (c1[0]+c1[1]) + (c1[2]+c1[3]);
            sq[n]  = c0[0]*c0[0] + c0[1]*c0[1] + c0[2]*c0[2] + c0[3]*c0[3]
                   + c1[0]*c1[0] + c1[1]*c1[1] + c1[2]*c1[2] + c1[3]*c1[3];
        }
        #pragma unroll
        for (int n = 0; n < 4; ++n) {
            sum[n] += __shfl_xor(sum[n], 16); sum[n] += __shfl_xor(sum[n], 32);
            sq[n]  += __shfl_xor(sq[n], 16);  sq[n]  += __shfl_xor(sq[n], 32);
        }
        if (l < 16) {
            #pragma unroll
            for (int n = 0; n < 4; ++n) {
                s1sum[(size_t)blk*8192 + m*64 + n*16 + l] = sum[n];
                s1sq [(size_t)blk*8192 + m*64 + n*16 + l] = sq[n];
            }
        }
    }
}

// ---------- finalize (both layouts) ----------
__global__ __launch_bounds__(256) void k_fin(
    const float* __restrict__ sump, const float* __restrict__ sqp,
    const float* __restrict__ bias, const float* __restrict__ gamma,
    const float* __restrict__ beta, float* __restrict__ scale,
    float* __restrict__ shift, int nfeat, int parts, int slotMajor)
{
    int f = blockIdx.x*256 + threadIdx.x;
    if (f >= nfeat) return;
    float S = 0.f, Q = 0.f;
    if (slotMajor) {
        #pragma unroll 8
        for (int c = 0; c < parts; ++c) { S += sump[(size_t)c*nfeat + f]; Q += sqp[(size_t)c*nfeat + f]; }
    } else {
        #pragma unroll 8
        for (int c = 0; c < parts; ++c) { S += sump[(size_t)f*parts + c]; Q += sqp[(size_t)f*parts + c]; }
    }
    float mz   = S * (1.f/BATCH);
    float var  = Q * (1.f/BATCH) - mz*mz;     // shift-invariant
    float mean = mz + bias[f];
    float sc   = rsqrtf(var + EPSV) * gamma[f];
    scale[f] = sc; shift[f] = beta[f] - mean*sc;
}

// ---------- k_stats2_p: recompute z1 -> BN1+ReLU -> dense2, stats of z2 ----------
__global__ __launch_bounds__(256) void k_stats2_p(
    const unsigned short* __restrict__ Ag, const unsigned short* __restrict__ W1p,
    const float* __restrict__ scale1, const float* __restrict__ shift1,
    const unsigned short* __restrict__ W2p,
    float* __restrict__ sum2p, float* __restrict__ sq2p)
{
    __shared__ unsigned short h1T[4][16*72];
    const int m = blockIdx.x >> 4, chunk = blockIdx.x & 15;
    const int t = threadIdx.x, w = t >> 6, l = t & 63;
    const int lr = l & 15, lg = l >> 4;
    short8 w1f[4];
    #pragma unroll
    for (int n = 0; n < 4; ++n) w1f[n] = *(const short8*)(W1p + m*2048 + n*512 + l*8);
    short8 w2f[2][2];
    #pragma unroll
    for (int n2 = 0; n2 < 2; ++n2)
        #pragma unroll
        for (int ks = 0; ks < 2; ++ks)
            w2f[n2][ks] = *(const short8*)(W2p + m*2048 + (n2*2+ks)*512 + l*8);
    float sc1[4], sh1[4];
    #pragma unroll
    for (int n = 0; n < 4; ++n) {
        sc1[n] = scale1[m*L1 + n*16 + lr];
        sh1[n] = shift1[m*L1 + n*16 + lr];
    }
    unsigned short* hT = &h1T[w][0];
    float sum[2] = {0,0}, sq[2] = {0,0};
    for (int i = 0; i < 8; ++i) {
        const int rbG = chunk*32 + i*4 + w;
        const short8 a = *(const short8*)(Ag + ((size_t)rbG*NM + m)*512 + lr*32 + lg*8);
        #pragma unroll
        for (int n = 0; n < 4; ++n) {
            f32x4 acc = {0.f,0.f,0.f,0.f};
            acc = __builtin_amdgcn_mfma_f32_16x16x32_bf16(a, w1f[n], acc, 0, 0, 0);
            #pragma unroll
            for (int r = 0; r < 4; ++r) {
                float h = acc[r]*sc1[n] + sh1[n];
                hT[(lg*4+r)*72 + n*16 + lr] = f2bf(h > 0.f ? h : 0.f);
            }
        }
        #pragma unroll
        for (int n2 = 0; n2 < 2; ++n2) {
            f32x4 acc = {0.f,0.f,0.f,0.f};
            #pragma unroll
            for (int ks = 0; ks < 2; ++ks) {
                const short8 a2 = *(const short8*)(hT + lr*72 + ks*32 + lg*8);
                acc = __builtin_amdgcn_mfma_f32_16x16x32_bf16(a2, w2f[n2][ks], acc, 0, 0, 0);
            }
            sum[n2] += (acc[0]+acc[1]) + (acc[2]+acc[3]);
            sq[n2]  += acc[0]*acc[0] + acc[1]*acc[1] + acc[2]*acc[2] + acc[3]*acc[3];
        }
    }
    #pragma unroll
    for (int n2 = 0; n2 < 2; ++n2) {
        sum[n2] += __shfl_xor(sum[n2], 16); sum[n2] += __shfl_xor(sum[n2], 32);
        sq[n2]  += __shfl_xor(sq[n2], 16);  sq[n2]  += __shfl_xor(sq[n2], 32);
    }
    if (l < 16) {
        const int slot = chunk*4 + w;
        #pragma unroll
        for (int n2 = 0; n2 < 2; ++n2) {
            const int f = m*L2O + n2*16 + l;
            sum2p[(size_t)f*P64 + slot] = sum[n2];
            sq2p [(size_t)f*P64 + slot] = sq[n2];
        }
    }
}

// ---------- k_final_p: full recompute -> pred (float4 stores) + outpartT ----------
__global__ __launch_bounds__(256) void k_final_p(
    const unsigned short* __restrict__ Ag, const unsigned short* __restrict__ W1p,
    const float* __restrict__ scale1, const float* __restrict__ shift1,
    const unsigned short* __restrict__ W2p,
    const float* __restrict__ scale2, const float* __restrict__ shift2,
    const unsigned short* __restrict__ W3p, const float* __restrict__ b3,
    const float* __restrict__ ow,
    float* __restrict__ pred, float* __restrict__ outpartT)
{
    __shared__ unsigned short h1T[4][16*72];
    __shared__ unsigned short h2T[4][16*40];
    const int m = blockIdx.x >> 4, chunk = blockIdx.x & 15;
    const int t = threadIdx.x, w = t >> 6, l = t & 63;
    const int lr = l & 15, lg = l >> 4;
    short8 w1f[4];
    #pragma unroll
    for (int n = 0; n < 4; ++n) w1f[n] = *(const short8*)(W1p + m*2048 + n*512 + l*8);
    short8 w2f[2][2];
    #pragma unroll
    for (int n2 = 0; n2 < 2; ++n2)
        #pragma unroll
        for (int ks = 0; ks < 2; ++ks)
            w2f[n2][ks] = *(const short8*)(W2p + m*2048 + (n2*2+ks)*512 + l*8);
    const short8 w3f = *(const short8*)(W3p + m*512 + l*8);
    float sc1[4], sh1[4];
    #pragma unroll
    for (int n = 0; n < 4; ++n) {
        sc1[n] = scale1[m*L1 + n*16 + lr];
        sh1[n] = shift1[m*L1 + n*16 + lr];
    }
    float sc2[2], sh2[2];
    #pragma unroll
    for (int n2 = 0; n2 < 2; ++n2) {
        sc2[n2] = scale2[m*L2O + n2*16 + lr];
        sh2[n2] = shift2[m*L2O + n2*16 + lr];
    }
    const float4 b3f = *(const float4*)(b3 + m*L3O + lg*4);
    const float4 owf = *(const float4*)(ow + m*L3O + lg*4);
    unsigned short* hT  = &h1T[w][0];
    unsigned short* hT2 = &h2T[w][0];
    for (int i = 0; i < 8; ++i) {
        const int rbG = chunk*32 + i*4 + w;
        const short8 a = *(const short8*)(Ag + ((size_t)rbG*NM + m)*512 + lr*32 + lg*8);
        #pragma unroll
        for (int n = 0; n < 4; ++n) {
            f32x4 acc = {0.f,0.f,0.f,0.f};
            acc = __builtin_amdgcn_mfma_f32_16x16x32_bf16(a, w1f[n], acc, 0, 0, 0);
            #pragma unroll
            for (int r = 0; r < 4; ++r) {
                float h = acc[r]*sc1[n] + sh1[n];
                hT[(lg*4+r)*72 + n*16 + lr] = f2bf(h > 0.f ? h : 0.f);
            }
        }
        #pragma unroll
        for (int n2 = 0; n2 < 2; ++n2) {
            f32x4 acc = {0.f,0.f,0.f,0.f};
            #pragma unroll
            for (int ks = 0; ks < 2; ++ks) {
                const short8 a2 = *(const short8*)(hT + lr*72 + ks*32 + lg*8);
                acc = __builtin_amdgcn_mfma_f32_16x16x32_bf16(a2, w2f[n2][ks], acc, 0, 0, 0);
            }
            #pragma unroll
            for (int r = 0; r < 4; ++r) {
                float h = acc[r]*sc2[n2] + sh2[n2];
                hT2[(lg*4+r)*40 + n2*16 + lr] = f2bf(h > 0.f ? h : 0.f);
            }
        }
        {
            const short8 a3 = *(const short8*)(hT2 + lr*40 + lg*8);
            f32x4 zz = {0.f,0.f,0.f,0.f};
            // swapped operands: D = (h2 . W3)^T -> lane lr = row, cols lg*4..lg*4+3
            f32x4 acc = __builtin_amdgcn_mfma_f32_16x16x32_bf16(w3f, a3, zz, 0, 0, 0);
            float4 pv;
            pv.x = acc[0] + b3f.x; pv.y = acc[1] + b3f.y;
            pv.z = acc[2] + b3f.z; pv.w = acc[3] + b3f.w;
            const size_t row = (size_t)rbG*16 + lr;
            *(float4*)(pred + row*(NM*L3O) + m*L3O + lg*4) = pv;
            float v = pv.x*owf.x + pv.y*owf.y + pv.z*owf.z + pv.w*owf.w;
            v += __shfl_xor(v, 16); v += __shfl_xor(v, 32);
            if (l < 16) outpartT[(size_t)m*BATCH + rbG*16 + l] = v;
        }
    }
}

// ---------- k_outT: out[b] = ob + sum_m outpartT[m][b] ----------
__global__ __launch_bounds__(256) void k_outT(
    const float* __restrict__ outpartT, const float* __restrict__ ob,
    float* __restrict__ out)
{
    int b = blockIdx.x*256 + threadIdx.x;
    float acc = ob[0];
    #pragma unroll 8
    for (int m = 0; m < NM; ++m) acc += outpartT[(size_t)m*BATCH + b];
    out[b] = acc;
}

// ---------- Path B fallback: separate gather + stats1 (round-3, verified) ----------
__global__ __launch_bounds__(256) void k_gather(
    const float* __restrict__ x, const int* __restrict__ uf,
    unsigned short* __restrict__ Ag)
{
    __shared__ float xs[16*INSZ];
    __shared__ int   sUf[NM*NF];
    const int rb = blockIdx.x;
    const int t  = threadIdx.x;
    const float4* xsrc = (const float4*)(x + (size_t)rb*16*INSZ);
    float4* xdst = (float4*)xs;
    #pragma unroll
    for (int p = 0; p < 8; ++p) xdst[t + p*256] = xsrc[t + p*256];
    const int4* us = (const int4*)uf;
    int4* ud = (int4*)sUf;
    #pragma unroll
    for (int p = 0; p < 4; ++p) ud[t + p*256] = us[t + p*256];
    __syncthreads();
    unsigned* outp = (unsigned*)(Ag + (size_t)rb*NM*512);
    const int e = t*2, r = e >> 5, j = e & 31;
    for (int m = 0; m < NM; ++m) {
        const int i0 = sUf[m*NF + j], i1 = sUf[m*NF + j + 1];
        outp[m*256 + t] = pkbf(xs[r*INSZ + i0], xs[r*INSZ + i1]);
    }
}

__global__ __launch_bounds__(256) void k_stats1_m(
    const unsigned short* __restrict__ Ag, const unsigned short* __restrict__ W1p,
    float* __restrict__ sum1p, float* __restrict__ sq1p)
{
    const int m = blockIdx.x >> 4, chunk = blockIdx.x & 15;
    const int t = threadIdx.x, w = t >> 6, l = t & 63;
    const int lr = l & 15, lg = l >> 4;
    short8 w1f[4];
    #pragma unroll
    for (int n = 0; n < 4; ++n) w1f[n] = *(const short8*)(W1p + m*2048 + n*512 + l*8);
    float sum[4] = {0,0,0,0}, sq[4] = {0,0,0,0};
    for (int i = 0; i < 8; ++i) {
        const int rbG = chunk*32 + i*4 + w;
        const short8 a = *(const short8*)(Ag + ((size_t)rbG*NM + m)*512 + lr*32 + lg*8);
        #pragma unroll
        for (int n = 0; n < 4; ++n) {
            f32x4 acc = {0.f,0.f,0.f,0.f};
            acc = __builtin_amdgcn_mfma_f32_16x16x32_bf16(a, w1f[n], acc, 0, 0, 0);
            sum[n] += (acc[0]+acc[1]) + (acc[2]+acc[3]);
            sq[n]  += acc[0]*acc[0] + acc[1]*acc[1] + acc[2]*acc[2] + acc[3]*acc[3];
        }
    }
    #pragma unroll
    for (int n = 0; n < 4; ++n) {
        sum[n] += __shfl_xor(sum[n], 16); sum[n] += __shfl_xor(sum[n], 32);
        sq[n]  += __shfl_xor(sq[n], 16);  sq[n]  += __shfl_xor(sq[n], 32);
    }
    if (l < 16) {
        const int slot = chunk*4 + w;
        #pragma unroll
        for (int n = 0; n < 4; ++n) {
            const int f = m*L1 + n*16 + l;
            sum1p[(size_t)f*P64 + slot] = sum[n];
            sq1p [(size_t)f*P64 + slot] = sq[n];
        }
    }
}

extern "C" void kernel_launch(void* const* d_in, const int* in_sizes, int n_in,
                              void* d_out, int out_size, void* d_ws, size_t ws_size,
                              hipStream_t stream) {
    const float* x   = (const float*)d_in[0];
    const int*   uf  = (const int*  )d_in[1];
    const float* W1  = (const float*)d_in[2];
    const float* b1  = (const float*)d_in[3];
    const float* W2  = (const float*)d_in[4];
    const float* b2  = (const float*)d_in[5];
    const float* W3  = (const float*)d_in[6];
    const float* b3  = (const float*)d_in[7];
    const float* g1  = (const float*)d_in[8];
    const float* be1 = (const float*)d_in[9];
    const float* g2  = (const float*)d_in[10];
    const float* be2 = (const float*)d_in[11];
    const float* ow  = (const float*)d_in[12];
    const float* ob  = (const float*)d_in[13];

    float* out  = (float*)d_out;
    float* pred = out + BATCH;

    // common workspace prefix
    const size_t agElems = (size_t)BATCH * NM * NF;        // bf16: 67,108,864 B
    unsigned short* Ag  = (unsigned short*)d_ws;
    unsigned short* W1p = Ag + agElems;                    // NM*2048
    unsigned short* W2p = W1p + NM*2048;                   // NM*2048
    unsigned short* W3p = W2p + NM*2048;                   // NM*512
    float* scale1 = (float*)(W3p + NM*512);
    float* shift1 = scale1 + NM*L1;
    float* scale2 = shift1 + NM*L1;
    float* shift2 = scale2 + NM*L2O;
    float* arena  = shift2 + NM*L2O;
    const size_t prefixBytes = (char*)arena - (char*)d_ws;

    const size_t arenaA = (size_t)GS1B*8192*4*2;                       // 16 MB
    const size_t s2Bytes = (size_t)NM*L2O*P64*4*2;                     // 2 MB
    const size_t needA = prefixBytes + arenaA;                          // ~85.2 MB
    const size_t arenaB = (size_t)NM*L1*P64*4*2;                       // 4 MB (stats1 / outpartT shared)
    const size_t needB = prefixBytes + arenaB + s2Bytes;               // ~74.7 MB

    k_prep<<<NM*4608/256, 256, 0, stream>>>(W1, W2, W3, W1p, W2p, W3p);

    if (ws_size >= needA) {
        float* s1sum = arena;                       // [256][8192]
        float* s1sq  = s1sum + (size_t)GS1B*8192;
        float* s2sum = arena;                       // reuse after fin1
        float* s2sq  = s2sum + (size_t)NM*L2O*P64;
        float* outpartT = arena;                    // reuse after fin2

        k_gs1<<<GS1B, 512, 0, stream>>>(x, uf, W1p, Ag, s1sum, s1sq);
        k_fin<<<NM*L1/256, 256, 0, stream>>>(s1sum, s1sq, b1, g1, be1, scale1, shift1, NM*L1, GS1B, 1);
        k_stats2_p<<<NM*CH, 256, 0, stream>>>(Ag, W1p, scale1, shift1, W2p, s2sum, s2sq);
        k_fin<<<NM*L2O/256, 256, 0, stream>>>(s2sum, s2sq, b2, g2, be2, scale2, shift2, NM*L2O, P64, 0);
        k_final_p<<<NM*CH, 256, 0, stream>>>(Ag, W1p, scale1, shift1, W2p, scale2, shift2,
                                             W3p, b3, ow, pred, outpartT);
        k_outT<<<BATCH/256, 256, 0, stream>>>(outpartT, ob, out);
    } else {
        float* s1sum = arena;                       // [8192][64] f-major
        float* s1sq  = s1sum + (size_t)NM*L1*P64;
        float* outpartT = arena;                    // reuse after fin1+stats2... (fin1 consumes before final)
        float* s2sum = arena + arenaB/4;
        float* s2sq  = s2sum + (size_t)NM*L2O*P64;

        k_gather<<<BATCH/16, 256, 0, stream>>>(x, uf, Ag);
        k_stats1_m<<<NM*CH, 256, 0, stream>>>(Ag, W1p, s1sum, s1sq);
        k_fin<<<NM*L1/256, 256, 0, stream>>>(s1sum, s1sq, b1, g1, be1, scale1, shift1, NM*L1, P64, 0);
        k_stats2_p<<<NM*CH, 256, 0, stream>>>(Ag, W1p, scale1, shift1, W2p, s2sum, s2sq);
        k_fin<<<NM*L2O/256, 256, 0, stream>>>(s2sum, s2sq, b2, g2, be2, scale2, shift2, NM*L2O, P64, 0);
        k_final_p<<<NM*CH, 256, 0, stream>>>(Ag, W1p, scale1, shift1, W2p, scale2, shift2,
                                             W3p, b3, ow, pred, outpartT);
        k_outT<<<BATCH/256, 256, 0, stream>>>(outpartT, ob, out);
    }
}